// Round 18
// baseline (200.866 us; speedup 1.0000x reference)
//
#include <hip/hip_runtime.h>
#include <math.h>

// FourierCrossAttention: B=16, L=4096, H=8, E=EO=64, MODES=64 (lowest)
// R18: k1 A-table dedup — one block processes BOTH q and k for its (bh,seg):
// A-fragments loaded once per tile, used for two MFMA phases (slots q,k).
// A-traffic 256MB -> 128MB (pipe model 540 -> 428MB). S=4 (3 partial sets,
// absorbed into k2a/k2b 4-term staging sums). Pipeline = proven R16 shape:
// 3-buf rotation, depth-2, uniform vmcnt(12).

constexpr float TWOPI_L = 1.5339807878856412e-3f;  // 2*pi/4096

typedef __attribute__((ext_vector_type(8))) short short8;
typedef __attribute__((ext_vector_type(4))) float f32x4;

__device__ __forceinline__ unsigned short f2bf(float f) {
    unsigned int u = __builtin_bit_cast(unsigned int, f);
    unsigned int r = (u + 0x7fffu + ((u >> 16) & 1u)) >> 16;
    return (unsigned short)r;
}
__device__ __forceinline__ float bf2f(unsigned short h) {
    unsigned int u = ((unsigned int)h) << 16;
    return __builtin_bit_cast(float, u);
}
__device__ __forceinline__ unsigned int cvtpk(float a, float b) {
    unsigned int r;
    asm("v_cvt_pk_bf16_f32 %0, %1, %2" : "=v"(r) : "v"(a), "v"(b));
    return r;
}
// async global->LDS, 16B per lane, dest = wave-uniform base + lane*16
__device__ __forceinline__ void gld16(const float* g, void* l) {
    __builtin_amdgcn_global_load_lds(
        (const __attribute__((address_space(1))) void*)(g),
        (__attribute__((address_space(3))) void*)(l),
        16, 0, 0);
}
// raw-buffer swizzle mask (float4-quad index XOR), row-local 0..63
#define MSKR(r) (((((r) & 7)) << 1) | ((((r) >> 3)) & 1))

// ---------------- KPREP: k0_twiddle (blocks 0..127) + kwt (blocks 128..639) ----------------
__global__ __launch_bounds__(256) void kprep(unsigned short* __restrict__ Whi,
                                             unsigned short* __restrict__ Wlo,
                                             const float* __restrict__ w1,
                                             const float* __restrict__ w2,
                                             float* __restrict__ wT)
{
    __shared__ float s1[64][65];
    __shared__ float s2[64][65];
    const int blk = blockIdx.x;
    const int tid = threadIdx.x;
    if (blk < 128) {
        const int idx = blk * 256 + tid;    // 32768 threads
        const int kt = idx >> 9;            // 0..63
        const int rb = (idx >> 6) & 7;      // 0..7
        const int l15 = (idx >> 2) & 15;    // 0..15
        const int lg = idx & 3;             // 0..3
        const int r_tab = rb * 16 + l15;
        int m, c;
        if (r_tab < 64) { m = (r_tab >> 1) * 2;              c = r_tab & 1; }
        else            { m = (((r_tab - 64) >> 1) * 2) + 1; c = r_tab & 1; }
        const int addr = (kt * 8 + rb) * 512 + l15 * 32 + lg * 8;
        unsigned short hbuf[8], lbuf[8];
#pragma unroll
        for (int j = 0; j < 8; ++j) {
            const int t = kt * 32 + lg * 8 + j;
            float sv, cv;
            sincosf((float)((m * t) & 4095) * TWOPI_L, &sv, &cv);
            const float v = c ? -sv : cv;
            const unsigned short hi = f2bf(v);
            hbuf[j] = hi;
            lbuf[j] = f2bf(v - bf2f(hi));
        }
        *(uint4*)(Whi + addr) = *(uint4*)hbuf;
        *(uint4*)(Wlo + addr) = *(uint4*)lbuf;
    } else {
        const int wblk = blk - 128;        // h*64 + e
        const int h = wblk >> 6, e = wblk & 63;
        const float* w1b = w1 + (size_t)(h * 64 + e) * 4096u;
        const float* w2b = w2 + (size_t)(h * 64 + e) * 4096u;
#pragma unroll
        for (int p = 0; p < 4; ++p) {
            const int f4 = tid + p * 256;            // 1024 float4s per array
            const int o = f4 >> 4, m4 = (f4 & 15) * 4;
            *(float4*)&s1[o][m4] = *(const float4*)(w1b + f4 * 4);
            *(float4*)&s2[o][m4] = *(const float4*)(w2b + f4 * 4);
        }
        __syncthreads();
        float* dstb = wT + ((size_t)(h * 64) * 64u + (size_t)e) * 128u;   // + m*8192
#pragma unroll
        for (int p = 0; p < 8; ++p) {
            const int f4 = tid + p * 256;            // 2048 float4s out
            const int m = f4 >> 5, c4 = f4 & 31;
            const int o = c4 * 2;
            const float4 v = make_float4(s1[o][m], s2[o][m], s1[o + 1][m], s2[o + 1][m]);
            *(float4*)(dstb + (size_t)m * 8192u + c4 * 4) = v;
        }
    }
}

// ---------------- K1: gll-staged folded MFMA DFT, q+k merged (A shared), S=4 ----------------
// Grid 512 = bh(128) x seg(4). 32 slots/block: tile i = s>>1, src = s&1.
__global__ __launch_bounds__(256, 2) void k1_mfma(const float* __restrict__ q,
                                                  const float* __restrict__ kin,
                                                  const unsigned short* __restrict__ Whi,
                                                  const unsigned short* __restrict__ Wlo,
                                                  float* __restrict__ Xq, float* __restrict__ Xk,
                                                  float* __restrict__ Pq, float* __restrict__ Pk)
{
    __shared__ float raw[3][64][64];            // 3-buf rotation, 48 KB
    __shared__ unsigned short xT[4][64][40];    // xp_hi/lo, xm_hi/lo, 20.5 KB

    const int tid = threadIdx.x;
    const int bid = blockIdx.x;
    const int bh = bid >> 2, seg = bid & 3;
    const int b = bh >> 3, h = bh & 7;
    const float* xqb = q   + (size_t)b * 2097152u + (size_t)h * 64u;
    const float* xkb = kin + (size_t)b * 2097152u + (size_t)h * 64u;

    const int wid = tid >> 6, lane = tid & 63;
    const int l15 = lane & 15, lg = lane >> 4;
    const int fp = (tid & 15) * 2;       // convert: t-pair rows fp, fp+1
    const int eqs = tid >> 4;            // convert: e-quad 0..15
    const int sel = (wid >> 1) * 2;      // waves 0,1: xp; waves 2,3: xm

    f32x4 accQ[2][4], accK[2][4];
#pragma unroll
    for (int mt = 0; mt < 2; ++mt)
#pragma unroll
        for (int nt = 0; nt < 4; ++nt) {
            accQ[mt][nt] = (f32x4){0.f, 0.f, 0.f, 0.f};
            accK[mt][nt] = (f32x4){0.f, 0.f, 0.f, 0.f};
        }

// stage slot SLOT (src = SLOT&1, tile = SLOT>>1) into raw[BUF]
#define K1_STAGE(SLOT, BUF) do {                                                \
    const int sl_ = (SLOT) & 31;                                                \
    const float* xb_ = (sl_ & 1) ? xkb : xqb;                                   \
    const int t0_ = (seg * 16 + (sl_ >> 1)) * 32;                               \
    float* rbase_ = &raw[BUF][0][0];                                            \
    _Pragma("unroll")                                                           \
    for (int j = 0; j < 4; ++j) {                                               \
        const int c_ = wid * 4 + j;                                             \
        const int rl_ = 4 * c_ + (lane >> 4);                                   \
        const int t_ = t0_ + (rl_ & 31) + ((rl_ >> 5) << 11);                   \
        const int sq_ = (lane & 15) ^ MSKR(rl_);                                \
        gld16(xb_ + (size_t)t_ * 512u + (size_t)(sq_ * 4), rbase_ + c_ * 256);  \
    }                                                                           \
} while (0)

#define K1_ALOAD(I, AH, AL) do {                                                \
    const int ksg_ = seg * 16 + ((I) & 15);                                     \
    _Pragma("unroll")                                                           \
    for (int mt = 0; mt < 2; ++mt) {                                            \
        const size_t o_ = (size_t)((ksg_ * 8 + (wid * 2 + mt)) * 512 + l15 * 32 + lg * 8); \
        AH[mt] = *(const short8*)(Whi + o_);                                    \
        AL[mt] = *(const short8*)(Wlo + o_);                                    \
    }                                                                           \
} while (0)

#define K1_CONVERT(BUF) do {                                                    \
    const float* rb_ = &raw[BUF][0][0];                                         \
    float rs[16];                                                               \
    *(f32x4*)&rs[0]  = *(const f32x4*)(rb_ + (fp     ) * 64 + ((eqs ^ MSKR(fp))      * 4)); \
    *(f32x4*)&rs[4]  = *(const f32x4*)(rb_ + (fp + 1 ) * 64 + ((eqs ^ MSKR(fp + 1))  * 4)); \
    *(f32x4*)&rs[8]  = *(const f32x4*)(rb_ + (fp + 32) * 64 + ((eqs ^ MSKR(fp + 32)) * 4)); \
    *(f32x4*)&rs[12] = *(const f32x4*)(rb_ + (fp + 33) * 64 + ((eqs ^ MSKR(fp + 33)) * 4)); \
    _Pragma("unroll")                                                           \
    for (int ee = 0; ee < 4; ++ee) {                                            \
        const float a0 = rs[ee], a1 = rs[4 + ee];                               \
        const float c0 = rs[8 + ee], c1 = rs[12 + ee];                          \
        const float xp0 = a0 + c0, xp1 = a1 + c1;                               \
        const float xm0 = a0 - c0, xm1 = a1 - c1;                               \
        const int e_ = eqs * 4 + ee;                                            \
        const unsigned int php = cvtpk(xp0, xp1);                               \
        const float ph0 = __builtin_bit_cast(float, php << 16);                 \
        const float ph1 = __builtin_bit_cast(float, php & 0xffff0000u);         \
        const unsigned int plp = cvtpk(xp0 - ph0, xp1 - ph1);                   \
        const unsigned int mhp = cvtpk(xm0, xm1);                               \
        const float mh0 = __builtin_bit_cast(float, mhp << 16);                 \
        const float mh1 = __builtin_bit_cast(float, mhp & 0xffff0000u);         \
        const unsigned int mlp = cvtpk(xm0 - mh0, xm1 - mh1);                   \
        *(unsigned int*)&xT[0][e_][fp] = php;                                   \
        *(unsigned int*)&xT[1][e_][fp] = plp;                                   \
        *(unsigned int*)&xT[2][e_][fp] = mhp;                                   \
        *(unsigned int*)&xT[3][e_][fp] = mlp;                                   \
    }                                                                           \
} while (0)

#define K1_MFMA(ACC, AH, AL) do {                                               \
    const unsigned short* sh = &xT[sel][0][0];                                  \
    const unsigned short* sl = &xT[sel + 1][0][0];                              \
    _Pragma("unroll")                                                           \
    for (int nt = 0; nt < 4; ++nt) {                                            \
        const int ri = (nt * 16 + l15) * 40 + 8 * lg;                           \
        const short8 Bh = *(const short8*)(sh + ri);                            \
        const short8 Bl = *(const short8*)(sl + ri);                            \
        _Pragma("unroll")                                                       \
        for (int mt = 0; mt < 2; ++mt)                                          \
            ACC[mt][nt] = __builtin_amdgcn_mfma_f32_16x16x32_bf16(AH[mt], Bh, ACC[mt][nt], 0, 0, 0); \
        _Pragma("unroll")                                                       \
        for (int mt = 0; mt < 2; ++mt)                                          \
            ACC[mt][nt] = __builtin_amdgcn_mfma_f32_16x16x32_bf16(AH[mt], Bl, ACC[mt][nt], 0, 0, 0); \
        _Pragma("unroll")                                                       \
        for (int mt = 0; mt < 2; ++mt)                                          \
            ACC[mt][nt] = __builtin_amdgcn_mfma_f32_16x16x32_bf16(AL[mt], Bh, ACC[mt][nt], 0, 0, 0); \
    }                                                                           \
} while (0)

// one (q,k) slot pair for tile PAIRI using A-set (AH,AL); prefetch A(PAIRI+1) into (NAH,NAL)
#define K1_PAIR(PAIRI, AH, AL, NAH, NAL) do {                                   \
    const int s0_ = 2 * (PAIRI);                                                \
    /* q slot */                                                                \
    K1_ALOAD((PAIRI) + 1, NAH, NAL);                                            \
    K1_STAGE(s0_ + 2, (s0_ + 2) % 3);                                           \
    __builtin_amdgcn_sched_barrier(0);                                          \
    asm volatile("s_waitcnt vmcnt(12)\n\ts_barrier" ::: "memory");              \
    K1_CONVERT(s0_ % 3);                                                        \
    asm volatile("s_waitcnt lgkmcnt(0)\n\ts_barrier" ::: "memory");             \
    K1_MFMA(accQ, AH, AL);                                                      \
    /* k slot */                                                                \
    K1_STAGE(s0_ + 3, (s0_ + 3) % 3);                                           \
    __builtin_amdgcn_sched_barrier(0);                                          \
    asm volatile("s_waitcnt vmcnt(12)\n\ts_barrier" ::: "memory");              \
    K1_CONVERT((s0_ + 1) % 3);                                                  \
    asm volatile("s_waitcnt lgkmcnt(0)\n\ts_barrier" ::: "memory");             \
    K1_MFMA(accK, AH, AL);                                                      \
} while (0)

    short8 AhA[2], AlA[2], AhB[2], AlB[2];
    // prologue: D(0) < A(0) < D(1); thereafter uniform vmcnt(12)
    K1_STAGE(0, 0);
    K1_ALOAD(0, AhA, AlA);
    K1_STAGE(1, 1);

    for (int pp = 0; pp < 8; ++pp) {
        K1_PAIR(2 * pp,     AhA, AlA, AhB, AlB);   // even pair: set A
        K1_PAIR(2 * pp + 1, AhB, AlB, AhA, AlA);   // odd pair:  set B
    }
    asm volatile("s_waitcnt vmcnt(0)" ::: "memory");   // drain wrapped tail DMAs

#undef K1_PAIR
#undef K1_MFMA
#undef K1_CONVERT
#undef K1_ALOAD
#undef K1_STAGE

    // C-write (verified mapping), q and k:
    float* Xdq = (seg == 0) ? Xq : (Pq + (size_t)(seg - 1) * 1048576u);
    float* Xdk = (seg == 0) ? Xk : (Pk + (size_t)(seg - 1) * 1048576u);
    Xdq += (size_t)bh * 8192u;
    Xdk += (size_t)bh * 8192u;
    const int oddw = wid >> 1;
    const int wb = wid & 1;
#pragma unroll
    for (int mt = 0; mt < 2; ++mt) {
        const int r0 = (wb * 2 + mt) * 32 + 8 * lg + 2 * oddw;
#pragma unroll
        for (int nt = 0; nt < 4; ++nt) {
            const int e = nt * 16 + l15;
            *(float2*)(Xdq + (size_t)e * 128u + r0) =
                make_float2(accQ[mt][nt][0], accQ[mt][nt][1]);
            *(float2*)(Xdq + (size_t)e * 128u + r0 + 4) =
                make_float2(accQ[mt][nt][2], accQ[mt][nt][3]);
            *(float2*)(Xdk + (size_t)e * 128u + r0) =
                make_float2(accK[mt][nt][0], accK[mt][nt][1]);
            *(float2*)(Xdk + (size_t)e * 128u + r0 + 4) =
                make_float2(accK[mt][nt][2], accK[mt][nt][3]);
        }
    }
}

// ---------------- K2a: P1  xqk = (Xq+SumPq)^T . (Xk+SumPk), tanh -> P[bh][y][2x] ----------------
__global__ __launch_bounds__(256) void k2a_p1(const float* __restrict__ Xq,
                                              const float* __restrict__ Xk,
                                              const float* __restrict__ Pq,
                                              const float* __restrict__ Pk,
                                              float* __restrict__ P)
{
    const int blk = blockIdx.x;
    const int bh = blk >> 2, xt = blk & 3;
    __shared__ float sQ[64 * 32];    // [e][2x-slice]
    __shared__ float sK[64 * 128];   // [e][2y]
    const int tid = threadIdx.x;
    const size_t boff = (size_t)bh * 8192u;

#pragma unroll
    for (int p = 0; p < 2; ++p) {
        const int f4 = tid + p * 256;           // 512 float4s
        const int row = f4 >> 3, c4 = f4 & 7;
        const size_t go = boff + (size_t)(row * 128 + xt * 32 + c4 * 4);
        float4 a = *(const float4*)(Xq + go);
#pragma unroll
        for (int s = 0; s < 3; ++s) {
            const float4 bb = *(const float4*)(Pq + (size_t)s * 1048576u + go);
            a.x += bb.x; a.y += bb.y; a.z += bb.z; a.w += bb.w;
        }
        *(float4*)&sQ[row * 32 + c4 * 4] = a;
    }
#pragma unroll
    for (int p = 0; p < 8; ++p) {
        const int f4 = tid + p * 256;           // 2048 float4s
        const size_t go = boff + (size_t)f4 * 4u;
        float4 a = *(const float4*)(Xk + go);
#pragma unroll
        for (int s = 0; s < 3; ++s) {
            const float4 bb = *(const float4*)(Pk + (size_t)s * 1048576u + go);
            a.x += bb.x; a.y += bb.y; a.z += bb.z; a.w += bb.w;
        }
        *(float4*)&sK[f4 * 4] = a;
    }
    __syncthreads();

    const int xg = tid & 15, yg = tid >> 4;
    float aR[4] = {0.f, 0.f, 0.f, 0.f}, aI[4] = {0.f, 0.f, 0.f, 0.f};
#pragma unroll 8
    for (int e = 0; e < 64; ++e) {
        const float2 qv = *(const float2*)&sQ[e * 32 + 2 * xg];
        const float4 k0 = *(const float4*)&sK[e * 128 + 8 * yg];
        const float4 k1v = *(const float4*)&sK[e * 128 + 8 * yg + 4];
        aR[0] += qv.x * k0.x - qv.y * k0.y;   aI[0] += qv.x * k0.y + qv.y * k0.x;
        aR[1] += qv.x * k0.z - qv.y * k0.w;   aI[1] += qv.x * k0.w + qv.y * k0.z;
        aR[2] += qv.x * k1v.x - qv.y * k1v.y; aI[2] += qv.x * k1v.y + qv.y * k1v.x;
        aR[3] += qv.x * k1v.z - qv.y * k1v.w; aI[3] += qv.x * k1v.w + qv.y * k1v.z;
    }
    float* Pb = P + (size_t)bh * 8192u;
    const int x_abs = xt * 16 + xg;
#pragma unroll
    for (int j = 0; j < 4; ++j) {
        const int y = 4 * yg + j;
        *(float2*)(Pb + (size_t)y * 128u + 2 * x_abs) =
            make_float2(tanhf(aR[j]), tanhf(aI[j]));
    }
}

// ---------------- K2B_BASIS: k2b (blocks 0..511, LK = Xk+SumPk) + k0_basis (512..767) ----------------
__global__ __launch_bounds__(256) void k2b_basis(const float* __restrict__ P,
                                                 const float* __restrict__ Xk,
                                                 const float* __restrict__ Pk,
                                                 float* __restrict__ PVG,
                                                 unsigned short* __restrict__ basis)
{
    __shared__ float sP[64 * 128];   // [y][2x]
    __shared__ float sKe[16 * 132];  // [e_loc][2y] pad->132
    const int blk = blockIdx.x;
    const int tid = threadIdx.x;
    if (blk >= 512) {
        const int idx = (blk - 512) * 256 + tid;   // 65536 threads x 4 pairs
        const int p0 = idx << 2;
        const int t = p0 >> 6;
        unsigned int pk[4];
#pragma unroll
        for (int j = 0; j < 4; ++j) {
            const int m = (p0 & 63) + j;
            float sv, cv;
            sincosf((float)((m * t) & 4095) * TWOPI_L, &sv, &cv);
            const float c = (m == 0) ? 1.0f : 2.0f * cv;
            const float s = (m == 0) ? 0.0f : -2.0f * sv;
            pk[j] = (unsigned int)f2bf(c) | ((unsigned int)f2bf(s) << 16);
        }
        *(uint4*)(basis + (size_t)t * 128u + ((p0 & 63) << 1)) =
            make_uint4(pk[0], pk[1], pk[2], pk[3]);
        return;
    }
    const int bh = blk >> 2, et = blk & 3;
    const int b = bh >> 3, h = bh & 7;
    const float* Pb = P + (size_t)bh * 8192u;
    const size_t koff = (size_t)bh * 8192u + (size_t)(et * 16) * 128u;

#pragma unroll
    for (int p = 0; p < 8; ++p) {
        const int f4 = tid + p * 256;
        *(float4*)&sP[f4 * 4] = *(const float4*)(Pb + f4 * 4);
    }
#pragma unroll
    for (int p = 0; p < 2; ++p) {
        const int f4 = tid + p * 256;           // 512 float4s
        const int row = f4 >> 5, c4 = f4 & 31;
        const size_t go = koff + (size_t)(row * 128 + c4 * 4);
        float4 a = *(const float4*)(Xk + go);
#pragma unroll
        for (int s = 0; s < 3; ++s) {
            const float4 bb = *(const float4*)(Pk + (size_t)s * 1048576u + go);
            a.x += bb.x; a.y += bb.y; a.z += bb.z; a.w += bb.w;
        }
        *(float4*)&sKe[row * 132 + c4 * 4] = a;
    }
    __syncthreads();

    const int xg = tid & 15, el = tid >> 4;
    float aR[4] = {0.f, 0.f, 0.f, 0.f}, aI[4] = {0.f, 0.f, 0.f, 0.f};
#pragma unroll 8
    for (int y = 0; y < 64; ++y) {
        const float2 kv = *(const float2*)&sKe[el * 132 + 2 * y];
        const float4 p0 = *(const float4*)&sP[y * 128 + 8 * xg];
        const float4 p1 = *(const float4*)&sP[y * 128 + 8 * xg + 4];
        aR[0] += p0.x * kv.x - p0.y * kv.y;   aI[0] += p0.x * kv.y + p0.y * kv.x;
        aR[1] += p0.z * kv.x - p0.w * kv.y;   aI[1] += p0.z * kv.y + p0.w * kv.x;
        aR[2] += p1.x * kv.x - p1.y * kv.y;   aI[2] += p1.x * kv.y + p1.y * kv.x;
        aR[3] += p1.z * kv.x - p1.w * kv.y;   aI[3] += p1.z * kv.y + p1.w * kv.x;
    }
    const int e_abs = et * 16 + el;
    float* base = PVG + (size_t)h * 131072u;   // per h: 64m*2c*16b*64e
#pragma unroll
    for (int j = 0; j < 4; ++j) {
        const int m = 4 * xg + j;
        base[(size_t)m * 2048u + 0u    + (size_t)b * 64u + e_abs] = aR[j];
        base[(size_t)m * 2048u + 1024u + (size_t)b * 64u + e_abs] = aI[j];
    }
}

// ---------------- K2c: P4  XW = PV . (w1 + i w2) -> XWT hi/lo bf16 ----------------
__global__ __launch_bounds__(256) void k2c_p4(const float* __restrict__ PVG,
                                              const float* __restrict__ wT,
                                              unsigned short* __restrict__ XWThi,
                                              unsigned short* __restrict__ XWTlo)
{
    const int blk = blockIdx.x;       // h*64 + m
    const int h = blk >> 6, m = blk & 63;
    __shared__ float sA[32 * 68];     // [c*16+b][e pad 68]
    __shared__ float sW[64 * 128];    // [e][2o]
    const int tid = threadIdx.x;
    const float* Ab = PVG + (size_t)h * 131072u + (size_t)m * 2048u;
    const float* Wb = wT + ((size_t)h * 64u + m) * 8192u;

#pragma unroll
    for (int p = 0; p < 2; ++p) {
        const int f4 = tid + p * 256;           // 512 float4s
        const int row = f4 >> 4, e0 = (f4 & 15) * 4;
        *(float4*)&sA[row * 68 + e0] = *(const float4*)(Ab + row * 64 + e0);
    }
#pragma unroll
    for (int p = 0; p < 8; ++p) {
        const int f4 = tid + p * 256;
        *(float4*)&sW[f4 * 4] = *(const float4*)(Wb + f4 * 4);
    }
    __syncthreads();

    const int og = tid & 15, b = tid >> 4;
    float aR[4] = {0.f, 0.f, 0.f, 0.f}, aI[4] = {0.f, 0.f, 0.f, 0.f};
#pragma unroll 8
    for (int e = 0; e < 64; ++e) {
        const float pR = sA[b * 68 + e];
        const float pI = sA[(16 + b) * 68 + e];
        const float4 w0 = *(const float4*)&sW[e * 128 + 8 * og];
        const float4 w1v = *(const float4*)&sW[e * 128 + 8 * og + 4];
        aR[0] += pR * w0.x - pI * w0.y;   aI[0] += pR * w0.y + pI * w0.x;
        aR[1] += pR * w0.z - pI * w0.w;   aI[1] += pR * w0.w + pI * w0.z;
        aR[2] += pR * w1v.x - pI * w1v.y; aI[2] += pR * w1v.y + pI * w1v.x;
        aR[3] += pR * w1v.z - pI * w1v.w; aI[3] += pR * w1v.w + pI * w1v.z;
    }
    const int bh = b * 8 + h;
    unsigned short* Th = XWThi + (size_t)bh * 8192u;
    unsigned short* Tl = XWTlo + (size_t)bh * 8192u;
#pragma unroll
    for (int j = 0; j < 4; ++j) {
        const int o = 4 * og + j;
        const unsigned int hp = cvtpk(aR[j], aI[j]);
        const float hR = __builtin_bit_cast(float, hp << 16);
        const float hI = __builtin_bit_cast(float, hp & 0xffff0000u);
        const unsigned int lp = cvtpk(aR[j] - hR, aI[j] - hI);
        *(unsigned int*)(Th + (size_t)o * 128u + 2 * m) = hp;
        *(unsigned int*)(Tl + (size_t)o * 128u + 2 * m) = lp;
    }
}

// ---------------- K3: MFMA irfft  out[4096t x 64o] = basis[4096x128] * XWT^T ----------------
__global__ __launch_bounds__(256, 3) void k3_mfma(const unsigned short* __restrict__ basis,
                                                  const unsigned short* __restrict__ XWThi,
                                                  const unsigned short* __restrict__ XWTlo,
                                                  float* __restrict__ out)
{
    const int bid = blockIdx.x;
    const int bh = bid >> 4, tc = bid & 15;
    const int b = bh >> 3, h = bh & 7;
    const int tid = threadIdx.x;
    const int wid = tid >> 6, lane = tid & 63;
    const int l15 = lane & 15, lg = lane >> 4;

    const int t0 = tc * 256 + wid * 64;
    const unsigned short* Th = XWThi + (size_t)bh * 8192u;
    const unsigned short* Tl = XWTlo + (size_t)bh * 8192u;

    f32x4 acc[4][4];
#pragma unroll
    for (int mt = 0; mt < 4; ++mt)
#pragma unroll
        for (int nt = 0; nt < 4; ++nt)
            acc[mt][nt] = (f32x4){0.f, 0.f, 0.f, 0.f};

#pragma unroll
    for (int ks = 0; ks < 4; ++ks) {
        const int ko = ks * 32 + 8 * lg;
        short8 A[4], Bh[4], Bl[4];
#pragma unroll
        for (int mt = 0; mt < 4; ++mt)
            A[mt] = *(const short8*)(basis + (size_t)(t0 + mt * 16 + l15) * 128u + ko);
#pragma unroll
        for (int nt = 0; nt < 4; ++nt) {
            Bh[nt] = *(const short8*)(Th + (size_t)(nt * 16 + l15) * 128u + ko);
            Bl[nt] = *(const short8*)(Tl + (size_t)(nt * 16 + l15) * 128u + ko);
        }
#pragma unroll
        for (int mt = 0; mt < 4; ++mt)
#pragma unroll
            for (int nt = 0; nt < 4; ++nt)
                acc[mt][nt] = __builtin_amdgcn_mfma_f32_16x16x32_bf16(A[mt], Bh[nt], acc[mt][nt], 0, 0, 0);
#pragma unroll
        for (int mt = 0; mt < 4; ++mt)
#pragma unroll
            for (int nt = 0; nt < 4; ++nt)
                acc[mt][nt] = __builtin_amdgcn_mfma_f32_16x16x32_bf16(A[mt], Bl[nt], acc[mt][nt], 0, 0, 0);
    }

    const float scale = 9.313225746154785e-10f;  // 2^-30
#pragma unroll
    for (int mt = 0; mt < 4; ++mt)
#pragma unroll
        for (int nt = 0; nt < 4; ++nt) {
            const int o = nt * 16 + l15;
#pragma unroll
            for (int j = 0; j < 4; ++j) {
                const int t = t0 + mt * 16 + 4 * lg + j;
                out[((size_t)(b * 4096 + t) * 8u + (size_t)h) * 64u + o] = acc[mt][nt][j] * scale;
            }
        }
}

extern "C" void kernel_launch(void* const* d_in, const int* in_sizes, int n_in,
                              void* d_out, int out_size, void* d_ws, size_t ws_size,
                              hipStream_t stream) {
    (void)in_sizes; (void)n_in; (void)out_size; (void)ws_size;
    const float* q  = (const float*)d_in[0];
    const float* k  = (const float*)d_in[1];
    // d_in[2] = v: unused by the reference forward
    const float* w1 = (const float*)d_in[3];
    const float* w2 = (const float*)d_in[4];
    float* out = (float*)d_out;

    // ws (12 MB): Xq [0,4MB) fl, Xk [4,8MB) fl, XWThi/lo [8,12MB) as bf16
    float* ws = (float*)d_ws;
    float* Xq = ws;
    float* Xk = ws + 1048576;
    unsigned short* XWThi = (unsigned short*)(ws + 2097152);   // 1,048,576 shorts
    unsigned short* XWTlo = XWThi + 1048576;
    unsigned short* basis = (unsigned short*)ws;               // overlays Xq AFTER k2a

    // d_out scratch (33.5M floats; all regions dead before k3 overwrites):
    unsigned short* Whi = (unsigned short*)out;                // 262,144 shorts (folded table)
    unsigned short* Wlo = Whi + 262144;                        // 262,144 shorts
    float* Pq  = out + 524288;                                 // 3 x 1M fl -> ends 3,670,016
    float* Pk  = out + 3670016;                                // 3 x 1M fl -> ends 6,815,744
    float* P   = out + 16777216;                               // 1M fl  (tanh'd xqk, [y][2x])
    float* wT  = out + 17825792;                               // 4M fl  [h][m][e][2o] -> 22,020,096
    float* PVG = out + 22020096;                               // 1M fl  [h][m][c][b][e]

    hipLaunchKernelGGL(kprep,     dim3(640),  dim3(256), 0, stream, Whi, Wlo, w1, w2, wT);
    hipLaunchKernelGGL(k1_mfma,   dim3(512),  dim3(256), 0, stream, q, k, Whi, Wlo, Xq, Xk, Pq, Pk);
    hipLaunchKernelGGL(k2a_p1,    dim3(512),  dim3(256), 0, stream, Xq, Xk, Pq, Pk, P);
    hipLaunchKernelGGL(k2b_basis, dim3(768),  dim3(256), 0, stream, P, Xk, Pk, PVG, basis);
    hipLaunchKernelGGL(k2c_p4,    dim3(512),  dim3(256), 0, stream, PVG, wT, XWThi, XWTlo);
    hipLaunchKernelGGL(k3_mfma,   dim3(2048), dim3(256), 0, stream, basis, XWThi, XWTlo, out);
}

// Round 19
// 188.285 us; speedup vs baseline: 1.0668x; 1.0668x over previous
//
#include <hip/hip_runtime.h>
#include <math.h>

// FourierCrossAttention: B=16, L=4096, H=8, E=EO=64, MODES=64 (lowest)
// R19 = R17 verbatim (best verified: 189.6us, absmax 7.28e-12).
// R18's A-dedup hit its pre-registered failure criterion (k1 112us, total
// 201us) -> reverted. k1 plateau ~105us = 1.2x its per-CU VMEM-byte model
// (540MB pipe traffic: x 268MB + A-from-L2 256MB + writes) — stable across
// 13 structural variants (R4-R18). k3 near write floor; tail = small
// latency-bound kernels + launch gaps.

constexpr float TWOPI_L = 1.5339807878856412e-3f;  // 2*pi/4096

typedef __attribute__((ext_vector_type(8))) short short8;
typedef __attribute__((ext_vector_type(4))) float f32x4;

__device__ __forceinline__ unsigned short f2bf(float f) {
    unsigned int u = __builtin_bit_cast(unsigned int, f);
    unsigned int r = (u + 0x7fffu + ((u >> 16) & 1u)) >> 16;
    return (unsigned short)r;
}
__device__ __forceinline__ float bf2f(unsigned short h) {
    unsigned int u = ((unsigned int)h) << 16;
    return __builtin_bit_cast(float, u);
}
__device__ __forceinline__ unsigned int cvtpk(float a, float b) {
    unsigned int r;
    asm("v_cvt_pk_bf16_f32 %0, %1, %2" : "=v"(r) : "v"(a), "v"(b));
    return r;
}
// async global->LDS, 16B per lane, dest = wave-uniform base + lane*16
__device__ __forceinline__ void gld16(const float* g, void* l) {
    __builtin_amdgcn_global_load_lds(
        (const __attribute__((address_space(1))) void*)(g),
        (__attribute__((address_space(3))) void*)(l),
        16, 0, 0);
}
// raw-buffer swizzle mask (float4-quad index XOR), row-local 0..63
#define MSKR(r) (((((r) & 7)) << 1) | ((((r) >> 3)) & 1))

// ---------------- KPREP: k0_twiddle (blocks 0..127) + kwt (blocks 128..639) ----------------
__global__ __launch_bounds__(256) void kprep(unsigned short* __restrict__ Whi,
                                             unsigned short* __restrict__ Wlo,
                                             const float* __restrict__ w1,
                                             const float* __restrict__ w2,
                                             float* __restrict__ wT)
{
    __shared__ float s1[64][65];
    __shared__ float s2[64][65];
    const int blk = blockIdx.x;
    const int tid = threadIdx.x;
    if (blk < 128) {
        const int idx = blk * 256 + tid;    // 32768 threads
        const int kt = idx >> 9;            // 0..63
        const int rb = (idx >> 6) & 7;      // 0..7
        const int l15 = (idx >> 2) & 15;    // 0..15
        const int lg = idx & 3;             // 0..3
        const int r_tab = rb * 16 + l15;
        int m, c;
        if (r_tab < 64) { m = (r_tab >> 1) * 2;              c = r_tab & 1; }
        else            { m = (((r_tab - 64) >> 1) * 2) + 1; c = r_tab & 1; }
        const int addr = (kt * 8 + rb) * 512 + l15 * 32 + lg * 8;
        unsigned short hbuf[8], lbuf[8];
#pragma unroll
        for (int j = 0; j < 8; ++j) {
            const int t = kt * 32 + lg * 8 + j;
            float sv, cv;
            sincosf((float)((m * t) & 4095) * TWOPI_L, &sv, &cv);
            const float v = c ? -sv : cv;
            const unsigned short hi = f2bf(v);
            hbuf[j] = hi;
            lbuf[j] = f2bf(v - bf2f(hi));
        }
        *(uint4*)(Whi + addr) = *(uint4*)hbuf;
        *(uint4*)(Wlo + addr) = *(uint4*)lbuf;
    } else {
        const int wblk = blk - 128;        // h*64 + e
        const int h = wblk >> 6, e = wblk & 63;
        const float* w1b = w1 + (size_t)(h * 64 + e) * 4096u;
        const float* w2b = w2 + (size_t)(h * 64 + e) * 4096u;
#pragma unroll
        for (int p = 0; p < 4; ++p) {
            const int f4 = tid + p * 256;            // 1024 float4s per array
            const int o = f4 >> 4, m4 = (f4 & 15) * 4;
            *(float4*)&s1[o][m4] = *(const float4*)(w1b + f4 * 4);
            *(float4*)&s2[o][m4] = *(const float4*)(w2b + f4 * 4);
        }
        __syncthreads();
        float* dstb = wT + ((size_t)(h * 64) * 64u + (size_t)e) * 128u;   // + m*8192
#pragma unroll
        for (int p = 0; p < 8; ++p) {
            const int f4 = tid + p * 256;            // 2048 float4s out
            const int m = f4 >> 5, c4 = f4 & 31;
            const int o = c4 * 2;
            const float4 v = make_float4(s1[o][m], s2[o][m], s1[o + 1][m], s2[o + 1][m]);
            *(float4*)(dstb + (size_t)m * 8192u + c4 * 4) = v;
        }
    }
}

// ---------------- K1: gll-staged folded MFMA DFT, depth-2, S=2 (32 tiles/block) ----------------
__global__ __launch_bounds__(256, 2) void k1_mfma(const float* __restrict__ q,
                                                  const float* __restrict__ kin,
                                                  const unsigned short* __restrict__ Whi,
                                                  const unsigned short* __restrict__ Wlo,
                                                  float* __restrict__ Xq, float* __restrict__ Xk,
                                                  float* __restrict__ Pq, float* __restrict__ Pk)
{
    __shared__ float raw[3][64][64];            // 3-buf rotation, 48 KB
    __shared__ unsigned short xT[4][64][40];    // xp_hi/lo, xm_hi/lo, 20.5 KB

    const int tid = threadIdx.x;
    const int bid = blockIdx.x;
    const int bh = bid >> 2, src = (bid >> 1) & 1, seg = bid & 1;
    const int b = bh >> 3, h = bh & 7;
    const float* __restrict__ x = src ? kin : q;
    const float* xb = x + (size_t)b * 2097152u + (size_t)h * 64u;

    const int wid = tid >> 6, lane = tid & 63;
    const int l15 = lane & 15, lg = lane >> 4;
    const int fp = (tid & 15) * 2;       // convert: t-pair rows fp, fp+1
    const int eqs = tid >> 4;            // convert: e-quad 0..15
    const int sel = (wid >> 1) * 2;      // waves 0,1: xp; waves 2,3: xm

    f32x4 acc[2][4];
#pragma unroll
    for (int mt = 0; mt < 2; ++mt)
#pragma unroll
        for (int nt = 0; nt < 4; ++nt)
            acc[mt][nt] = (f32x4){0.f, 0.f, 0.f, 0.f};

#define K1_STAGE(IT, BUF) do {                                                  \
    const int t0_ = (seg * 32 + ((IT) & 31)) * 32;                              \
    float* rbase_ = &raw[BUF][0][0];                                            \
    _Pragma("unroll")                                                           \
    for (int j = 0; j < 4; ++j) {                                               \
        const int c_ = wid * 4 + j;                                             \
        const int rl_ = 4 * c_ + (lane >> 4);                                   \
        const int t_ = t0_ + (rl_ & 31) + ((rl_ >> 5) << 11);                   \
        const int sq_ = (lane & 15) ^ MSKR(rl_);                                \
        gld16(xb + (size_t)t_ * 512u + (size_t)(sq_ * 4), rbase_ + c_ * 256);   \
    }                                                                           \
} while (0)

#define K1_ALOAD(IT, AH, AL) do {                                               \
    const int ksg_ = seg * 32 + ((IT) & 31);                                    \
    _Pragma("unroll")                                                           \
    for (int mt = 0; mt < 2; ++mt) {                                            \
        const size_t o_ = (size_t)((ksg_ * 8 + (wid * 2 + mt)) * 512 + l15 * 32 + lg * 8); \
        AH[mt] = *(const short8*)(Whi + o_);                                    \
        AL[mt] = *(const short8*)(Wlo + o_);                                    \
    }                                                                           \
} while (0)

#define K1_CONVERT(BUF) do {                                                    \
    const float* rb_ = &raw[BUF][0][0];                                         \
    float rs[16];                                                               \
    *(f32x4*)&rs[0]  = *(const f32x4*)(rb_ + (fp     ) * 64 + ((eqs ^ MSKR(fp))      * 4)); \
    *(f32x4*)&rs[4]  = *(const f32x4*)(rb_ + (fp + 1 ) * 64 + ((eqs ^ MSKR(fp + 1))  * 4)); \
    *(f32x4*)&rs[8]  = *(const f32x4*)(rb_ + (fp + 32) * 64 + ((eqs ^ MSKR(fp + 32)) * 4)); \
    *(f32x4*)&rs[12] = *(const f32x4*)(rb_ + (fp + 33) * 64 + ((eqs ^ MSKR(fp + 33)) * 4)); \
    _Pragma("unroll")                                                           \
    for (int ee = 0; ee < 4; ++ee) {                                            \
        const float a0 = rs[ee], a1 = rs[4 + ee];                               \
        const float c0 = rs[8 + ee], c1 = rs[12 + ee];                          \
        const float xp0 = a0 + c0, xp1 = a1 + c1;                               \
        const float xm0 = a0 - c0, xm1 = a1 - c1;                               \
        const int e_ = eqs * 4 + ee;                                            \
        const unsigned int php = cvtpk(xp0, xp1);                               \
        const float ph0 = __builtin_bit_cast(float, php << 16);                 \
        const float ph1 = __builtin_bit_cast(float, php & 0xffff0000u);         \
        const unsigned int plp = cvtpk(xp0 - ph0, xp1 - ph1);                   \
        const unsigned int mhp = cvtpk(xm0, xm1);                               \
        const float mh0 = __builtin_bit_cast(float, mhp << 16);                 \
        const float mh1 = __builtin_bit_cast(float, mhp & 0xffff0000u);         \
        const unsigned int mlp = cvtpk(xm0 - mh0, xm1 - mh1);                   \
        *(unsigned int*)&xT[0][e_][fp] = php;                                   \
        *(unsigned int*)&xT[1][e_][fp] = plp;                                   \
        *(unsigned int*)&xT[2][e_][fp] = mhp;                                   \
        *(unsigned int*)&xT[3][e_][fp] = mlp;                                   \
    }                                                                           \
} while (0)

#define K1_MFMA(AH, AL) do {                                                    \
    const unsigned short* sh = &xT[sel][0][0];                                  \
    const unsigned short* sl = &xT[sel + 1][0][0];                              \
    _Pragma("unroll")                                                           \
    for (int nt = 0; nt < 4; ++nt) {                                            \
        const int ri = (nt * 16 + l15) * 40 + 8 * lg;                           \
        const short8 Bh = *(const short8*)(sh + ri);                            \
        const short8 Bl = *(const short8*)(sl + ri);                            \
        _Pragma("unroll")                                                       \
        for (int mt = 0; mt < 2; ++mt)                                          \
            acc[mt][nt] = __builtin_amdgcn_mfma_f32_16x16x32_bf16(AH[mt], Bh, acc[mt][nt], 0, 0, 0); \
        _Pragma("unroll")                                                       \
        for (int mt = 0; mt < 2; ++mt)                                          \
            acc[mt][nt] = __builtin_amdgcn_mfma_f32_16x16x32_bf16(AH[mt], Bl, acc[mt][nt], 0, 0, 0); \
        _Pragma("unroll")                                                       \
        for (int mt = 0; mt < 2; ++mt)                                          \
            acc[mt][nt] = __builtin_amdgcn_mfma_f32_16x16x32_bf16(AL[mt], Bh, acc[mt][nt], 0, 0, 0); \
    }                                                                           \
} while (0)

    short8 AhA[2], AlA[2], AhB[2], AlB[2];
    // prologue: DMA(0) < A(0) < DMA(1)
    K1_STAGE(0, 0);
    K1_ALOAD(0, AhA, AlA);
    K1_STAGE(1, 1);

    for (int itp = 0; itp < 16; ++itp) {
        const int it0 = 2 * itp;
        const int be = it0 % 3, bo = (it0 + 1) % 3;
        const int bs1 = (it0 + 2) % 3, bs2 = (it0 + 3) % 3;
        // ---- even tile it0: A-set A ----
        K1_ALOAD(it0 + 1, AhB, AlB);
        K1_STAGE(it0 + 2, bs1);
        __builtin_amdgcn_sched_barrier(0);
        // newer than A(it0): DMA(it0+1)4 + A(it0+1)4 + DMA(it0+2)4 = 12
        asm volatile("s_waitcnt vmcnt(12)\n\ts_barrier" ::: "memory");
        K1_CONVERT(be);
        asm volatile("s_waitcnt lgkmcnt(0)\n\ts_barrier" ::: "memory");
        K1_MFMA(AhA, AlA);
        // ---- odd tile it0+1: A-set B ----
        K1_ALOAD(it0 + 2, AhA, AlA);
        K1_STAGE(it0 + 3, bs2);
        __builtin_amdgcn_sched_barrier(0);
        asm volatile("s_waitcnt vmcnt(12)\n\ts_barrier" ::: "memory");
        K1_CONVERT(bo);
        asm volatile("s_waitcnt lgkmcnt(0)\n\ts_barrier" ::: "memory");
        K1_MFMA(AhB, AlB);
    }
    asm volatile("s_waitcnt vmcnt(0)" ::: "memory");   // drain tail DMAs

#undef K1_MFMA
#undef K1_CONVERT
#undef K1_ALOAD
#undef K1_STAGE

    // C-write (R9/R13 verified mapping): X[e][128] layout unchanged downstream.
    float* Xd;
    if (seg == 0) Xd = src ? Xk : Xq;
    else          Xd = src ? Pk : Pq;
    Xd += (size_t)bh * 8192u;
    const int oddw = wid >> 1;
    const int wb = wid & 1;
#pragma unroll
    for (int mt = 0; mt < 2; ++mt) {
        const int r0 = (wb * 2 + mt) * 32 + 8 * lg + 2 * oddw;
#pragma unroll
        for (int nt = 0; nt < 4; ++nt) {
            const int e = nt * 16 + l15;
            *(float2*)(Xd + (size_t)e * 128u + r0) =
                make_float2(acc[mt][nt][0], acc[mt][nt][1]);
            *(float2*)(Xd + (size_t)e * 128u + r0 + 4) =
                make_float2(acc[mt][nt][2], acc[mt][nt][3]);
        }
    }
}

// ---------------- K2a: P1  xqk = (Xq+Pq)^T . (Xk+Pk), tanh -> P[bh][y][2x] ----------------
__global__ __launch_bounds__(256) void k2a_p1(const float* __restrict__ Xq,
                                              const float* __restrict__ Xk,
                                              const float* __restrict__ Pq,
                                              const float* __restrict__ Pk,
                                              float* __restrict__ P)
{
    const int blk = blockIdx.x;
    const int bh = blk >> 2, xt = blk & 3;
    __shared__ float sQ[64 * 32];    // [e][2x-slice]
    __shared__ float sK[64 * 128];   // [e][2y]
    const int tid = threadIdx.x;
    const size_t boff = (size_t)bh * 8192u;

#pragma unroll
    for (int p = 0; p < 2; ++p) {
        const int f4 = tid + p * 256;           // 512 float4s
        const int row = f4 >> 3, c4 = f4 & 7;
        const size_t go = boff + (size_t)(row * 128 + xt * 32 + c4 * 4);
        const float4 a = *(const float4*)(Xq + go);
        const float4 b = *(const float4*)(Pq + go);
        *(float4*)&sQ[row * 32 + c4 * 4] =
            make_float4(a.x + b.x, a.y + b.y, a.z + b.z, a.w + b.w);
    }
#pragma unroll
    for (int p = 0; p < 8; ++p) {
        const int f4 = tid + p * 256;           // 2048 float4s
        const float4 a = *(const float4*)(Xk + boff + (size_t)f4 * 4u);
        const float4 b = *(const float4*)(Pk + boff + (size_t)f4 * 4u);
        *(float4*)&sK[f4 * 4] =
            make_float4(a.x + b.x, a.y + b.y, a.z + b.z, a.w + b.w);
    }
    __syncthreads();

    const int xg = tid & 15, yg = tid >> 4;
    float aR[4] = {0.f, 0.f, 0.f, 0.f}, aI[4] = {0.f, 0.f, 0.f, 0.f};
#pragma unroll 8
    for (int e = 0; e < 64; ++e) {
        const float2 qv = *(const float2*)&sQ[e * 32 + 2 * xg];
        const float4 k0 = *(const float4*)&sK[e * 128 + 8 * yg];
        const float4 k1v = *(const float4*)&sK[e * 128 + 8 * yg + 4];
        aR[0] += qv.x * k0.x - qv.y * k0.y;   aI[0] += qv.x * k0.y + qv.y * k0.x;
        aR[1] += qv.x * k0.z - qv.y * k0.w;   aI[1] += qv.x * k0.w + qv.y * k0.z;
        aR[2] += qv.x * k1v.x - qv.y * k1v.y; aI[2] += qv.x * k1v.y + qv.y * k1v.x;
        aR[3] += qv.x * k1v.z - qv.y * k1v.w; aI[3] += qv.x * k1v.w + qv.y * k1v.z;
    }
    float* Pb = P + (size_t)bh * 8192u;
    const int x_abs = xt * 16 + xg;
#pragma unroll
    for (int j = 0; j < 4; ++j) {
        const int y = 4 * yg + j;
        *(float2*)(Pb + (size_t)y * 128u + 2 * x_abs) =
            make_float2(tanhf(aR[j]), tanhf(aI[j]));
    }
}

// ---------------- K2B_BASIS: k2b (blocks 0..511, LK = Xk+Pk) + k0_basis (512..767) ----------------
__global__ __launch_bounds__(256) void k2b_basis(const float* __restrict__ P,
                                                 const float* __restrict__ Xk,
                                                 const float* __restrict__ Pk,
                                                 float* __restrict__ PVG,
                                                 unsigned short* __restrict__ basis)
{
    __shared__ float sP[64 * 128];   // [y][2x]
    __shared__ float sKe[16 * 132];  // [e_loc][2y] pad->132
    const int blk = blockIdx.x;
    const int tid = threadIdx.x;
    if (blk >= 512) {
        const int idx = (blk - 512) * 256 + tid;   // 65536 threads x 4 pairs
        const int p0 = idx << 2;
        const int t = p0 >> 6;
        unsigned int pk[4];
#pragma unroll
        for (int j = 0; j < 4; ++j) {
            const int m = (p0 & 63) + j;
            float sv, cv;
            sincosf((float)((m * t) & 4095) * TWOPI_L, &sv, &cv);
            const float c = (m == 0) ? 1.0f : 2.0f * cv;
            const float s = (m == 0) ? 0.0f : -2.0f * sv;
            pk[j] = (unsigned int)f2bf(c) | ((unsigned int)f2bf(s) << 16);
        }
        *(uint4*)(basis + (size_t)t * 128u + ((p0 & 63) << 1)) =
            make_uint4(pk[0], pk[1], pk[2], pk[3]);
        return;
    }
    const int bh = blk >> 2, et = blk & 3;
    const int b = bh >> 3, h = bh & 7;
    const float* Pb = P + (size_t)bh * 8192u;
    const size_t koff = (size_t)bh * 8192u + (size_t)(et * 16) * 128u;

#pragma unroll
    for (int p = 0; p < 8; ++p) {
        const int f4 = tid + p * 256;
        *(float4*)&sP[f4 * 4] = *(const float4*)(Pb + f4 * 4);
    }
#pragma unroll
    for (int p = 0; p < 2; ++p) {
        const int f4 = tid + p * 256;           // 512 float4s
        const int row = f4 >> 5, c4 = f4 & 31;
        const size_t go = koff + (size_t)(row * 128 + c4 * 4);
        const float4 a = *(const float4*)(Xk + go);
        const float4 bb = *(const float4*)(Pk + go);
        *(float4*)&sKe[row * 132 + c4 * 4] =
            make_float4(a.x + bb.x, a.y + bb.y, a.z + bb.z, a.w + bb.w);
    }
    __syncthreads();

    const int xg = tid & 15, el = tid >> 4;
    float aR[4] = {0.f, 0.f, 0.f, 0.f}, aI[4] = {0.f, 0.f, 0.f, 0.f};
#pragma unroll 8
    for (int y = 0; y < 64; ++y) {
        const float2 kv = *(const float2*)&sKe[el * 132 + 2 * y];
        const float4 p0 = *(const float4*)&sP[y * 128 + 8 * xg];
        const float4 p1 = *(const float4*)&sP[y * 128 + 8 * xg + 4];
        aR[0] += p0.x * kv.x - p0.y * kv.y;   aI[0] += p0.x * kv.y + p0.y * kv.x;
        aR[1] += p0.z * kv.x - p0.w * kv.y;   aI[1] += p0.z * kv.y + p0.w * kv.x;
        aR[2] += p1.x * kv.x - p1.y * kv.y;   aI[2] += p1.x * kv.y + p1.y * kv.x;
        aR[3] += p1.z * kv.x - p1.w * kv.y;   aI[3] += p1.z * kv.y + p1.w * kv.x;
    }
    const int e_abs = et * 16 + el;
    float* base = PVG + (size_t)h * 131072u;   // per h: 64m*2c*16b*64e
#pragma unroll
    for (int j = 0; j < 4; ++j) {
        const int m = 4 * xg + j;
        base[(size_t)m * 2048u + 0u    + (size_t)b * 64u + e_abs] = aR[j];
        base[(size_t)m * 2048u + 1024u + (size_t)b * 64u + e_abs] = aI[j];
    }
}

// ---------------- K2c: P4  XW = PV . (w1 + i w2) -> XWT hi/lo bf16 ----------------
__global__ __launch_bounds__(256) void k2c_p4(const float* __restrict__ PVG,
                                              const float* __restrict__ wT,
                                              unsigned short* __restrict__ XWThi,
                                              unsigned short* __restrict__ XWTlo)
{
    const int blk = blockIdx.x;       // h*64 + m
    const int h = blk >> 6, m = blk & 63;
    __shared__ float sA[32 * 68];     // [c*16+b][e pad 68]
    __shared__ float sW[64 * 128];    // [e][2o]
    const int tid = threadIdx.x;
    const float* Ab = PVG + (size_t)h * 131072u + (size_t)m * 2048u;
    const float* Wb = wT + ((size_t)h * 64u + m) * 8192u;

#pragma unroll
    for (int p = 0; p < 2; ++p) {
        const int f4 = tid + p * 256;           // 512 float4s
        const int row = f4 >> 4, e0 = (f4 & 15) * 4;
        *(float4*)&sA[row * 68 + e0] = *(const float4*)(Ab + row * 64 + e0);
    }
#pragma unroll
    for (int p = 0; p < 8; ++p) {
        const int f4 = tid + p * 256;
        *(float4*)&sW[f4 * 4] = *(const float4*)(Wb + f4 * 4);
    }
    __syncthreads();

    const int og = tid & 15, b = tid >> 4;
    float aR[4] = {0.f, 0.f, 0.f, 0.f}, aI[4] = {0.f, 0.f, 0.f, 0.f};
#pragma unroll 8
    for (int e = 0; e < 64; ++e) {
        const float pR = sA[b * 68 + e];
        const float pI = sA[(16 + b) * 68 + e];
        const float4 w0 = *(const float4*)&sW[e * 128 + 8 * og];
        const float4 w1v = *(const float4*)&sW[e * 128 + 8 * og + 4];
        aR[0] += pR * w0.x - pI * w0.y;   aI[0] += pR * w0.y + pI * w0.x;
        aR[1] += pR * w0.z - pI * w0.w;   aI[1] += pR * w0.w + pI * w0.z;
        aR[2] += pR * w1v.x - pI * w1v.y; aI[2] += pR * w1v.y + pI * w1v.x;
        aR[3] += pR * w1v.z - pI * w1v.w; aI[3] += pR * w1v.w + pI * w1v.z;
    }
    const int bh = b * 8 + h;
    unsigned short* Th = XWThi + (size_t)bh * 8192u;
    unsigned short* Tl = XWTlo + (size_t)bh * 8192u;
#pragma unroll
    for (int j = 0; j < 4; ++j) {
        const int o = 4 * og + j;
        const unsigned int hp = cvtpk(aR[j], aI[j]);
        const float hR = __builtin_bit_cast(float, hp << 16);
        const float hI = __builtin_bit_cast(float, hp & 0xffff0000u);
        const unsigned int lp = cvtpk(aR[j] - hR, aI[j] - hI);
        *(unsigned int*)(Th + (size_t)o * 128u + 2 * m) = hp;
        *(unsigned int*)(Tl + (size_t)o * 128u + 2 * m) = lp;
    }
}

// ---------------- K3: MFMA irfft  out[4096t x 64o] = basis[4096x128] * XWT^T ----------------
__global__ __launch_bounds__(256, 3) void k3_mfma(const unsigned short* __restrict__ basis,
                                                  const unsigned short* __restrict__ XWThi,
                                                  const unsigned short* __restrict__ XWTlo,
                                                  float* __restrict__ out)
{
    const int bid = blockIdx.x;
    const int bh = bid >> 4, tc = bid & 15;
    const int b = bh >> 3, h = bh & 7;
    const int tid = threadIdx.x;
    const int wid = tid >> 6, lane = tid & 63;
    const int l15 = lane & 15, lg = lane >> 4;

    const int t0 = tc * 256 + wid * 64;
    const unsigned short* Th = XWThi + (size_t)bh * 8192u;
    const unsigned short* Tl = XWTlo + (size_t)bh * 8192u;

    f32x4 acc[4][4];
#pragma unroll
    for (int mt = 0; mt < 4; ++mt)
#pragma unroll
        for (int nt = 0; nt < 4; ++nt)
            acc[mt][nt] = (f32x4){0.f, 0.f, 0.f, 0.f};

#pragma unroll
    for (int ks = 0; ks < 4; ++ks) {
        const int ko = ks * 32 + 8 * lg;
        short8 A[4], Bh[4], Bl[4];
#pragma unroll
        for (int mt = 0; mt < 4; ++mt)
            A[mt] = *(const short8*)(basis + (size_t)(t0 + mt * 16 + l15) * 128u + ko);
#pragma unroll
        for (int nt = 0; nt < 4; ++nt) {
            Bh[nt] = *(const short8*)(Th + (size_t)(nt * 16 + l15) * 128u + ko);
            Bl[nt] = *(const short8*)(Tl + (size_t)(nt * 16 + l15) * 128u + ko);
        }
#pragma unroll
        for (int mt = 0; mt < 4; ++mt)
#pragma unroll
            for (int nt = 0; nt < 4; ++nt)
                acc[mt][nt] = __builtin_amdgcn_mfma_f32_16x16x32_bf16(A[mt], Bh[nt], acc[mt][nt], 0, 0, 0);
#pragma unroll
        for (int mt = 0; mt < 4; ++mt)
#pragma unroll
            for (int nt = 0; nt < 4; ++nt)
                acc[mt][nt] = __builtin_amdgcn_mfma_f32_16x16x32_bf16(A[mt], Bl[nt], acc[mt][nt], 0, 0, 0);
    }

    const float scale = 9.313225746154785e-10f;  // 2^-30
#pragma unroll
    for (int mt = 0; mt < 4; ++mt)
#pragma unroll
        for (int nt = 0; nt < 4; ++nt) {
            const int o = nt * 16 + l15;
#pragma unroll
            for (int j = 0; j < 4; ++j) {
                const int t = t0 + mt * 16 + 4 * lg + j;
                out[((size_t)(b * 4096 + t) * 8u + (size_t)h) * 64u + o] = acc[mt][nt][j] * scale;
            }
        }
}

extern "C" void kernel_launch(void* const* d_in, const int* in_sizes, int n_in,
                              void* d_out, int out_size, void* d_ws, size_t ws_size,
                              hipStream_t stream) {
    (void)in_sizes; (void)n_in; (void)out_size; (void)ws_size;
    const float* q  = (const float*)d_in[0];
    const float* k  = (const float*)d_in[1];
    // d_in[2] = v: unused by the reference forward
    const float* w1 = (const float*)d_in[3];
    const float* w2 = (const float*)d_in[4];
    float* out = (float*)d_out;

    // ws (12 MB): Xq [0,4MB) fl, Xk [4,8MB) fl, XWThi/lo [8,12MB) as bf16
    float* ws = (float*)d_ws;
    float* Xq = ws;
    float* Xk = ws + 1048576;
    unsigned short* XWThi = (unsigned short*)(ws + 2097152);   // 1,048,576 shorts
    unsigned short* XWTlo = XWThi + 1048576;
    unsigned short* basis = (unsigned short*)ws;               // overlays Xq AFTER k2a

    // d_out scratch (33.5M floats; all regions dead before k3 overwrites):
    unsigned short* Whi = (unsigned short*)out;                // 262,144 shorts (folded table)
    unsigned short* Wlo = Whi + 262144;                        // 262,144 shorts
    float* Pq  = out + 524288;                                 // 1M fl
    float* Pk  = out + 1572864;                                // 1M fl -> ends 2,621,440
    float* P   = out + 16777216;                               // 1M fl  (tanh'd xqk, [y][2x])
    float* wT  = out + 17825792;                               // 4M fl  [h][m][e][2o] -> 22,020,096
    float* PVG = out + 22020096;                               // 1M fl  [h][m][c][b][e]

    hipLaunchKernelGGL(kprep,     dim3(640),  dim3(256), 0, stream, Whi, Wlo, w1, w2, wT);
    hipLaunchKernelGGL(k1_mfma,   dim3(512),  dim3(256), 0, stream, q, k, Whi, Wlo, Xq, Xk, Pq, Pk);
    hipLaunchKernelGGL(k2a_p1,    dim3(512),  dim3(256), 0, stream, Xq, Xk, Pq, Pk, P);
    hipLaunchKernelGGL(k2b_basis, dim3(768),  dim3(256), 0, stream, P, Xk, Pk, PVG, basis);
    hipLaunchKernelGGL(k2c_p4,    dim3(512),  dim3(256), 0, stream, PVG, wT, XWThi, XWTlo);
    hipLaunchKernelGGL(k3_mfma,   dim3(2048), dim3(256), 0, stream, basis, XWThi, XWTlo, out);
}